// Round 8
// baseline (204.798 us; speedup 1.0000x reference)
//
#include <hip/hip_runtime.h>
#include <hip/hip_fp16.h>

#define N_NODES 50000
#define N_EDGES 1600000
#define IN_DIM 256
#define OUT_DIM 128
#define NEG_SLOPE 0.01f

// ---- two-level scatter, deterministic slots (ZERO global atomics) ----
#define SB_SH     10
#define SB_ROWS   1024
#define NSB       ((N_NODES + SB_ROWS - 1) / SB_ROWS)   // 49
#define SEG       208                                   // records per segment (+7 sigma)

#define BIN_SH    5
#define BIN_ROWS  32
#define NBIN      ((N_NODES + BIN_ROWS - 1) / BIN_ROWS) // 1563
#define NBIN_PAD  (NSB * 32)                            // 1568
#define NPART     8                                     // fine parts per super-bin
#define CAPB_TOT  (NPART * SEG)                         // 1664 max records/bin
#define OVF_CAP   65536

#define SCAT_BLOCKS 256
#define CONVW_BLOCKS 8
#define EPB_S (N_EDGES / SCAT_BLOCKS)    // 6250
#define SCAT_ITERS ((EPB_S + 511) / 512) // 13

typedef _Float16 f16x8 __attribute__((ext_vector_type(8)));
typedef float    f32x4 __attribute__((ext_vector_type(4)));
typedef float    f32x8 __attribute__((ext_vector_type(8)));

__device__ __forceinline__ float lrelu(float v) {
    return v >= 0.f ? v : NEG_SLOPE * v;
}

// ---------------------------------------------------------------------------
// Kernel 1: h = x @ W via v_mfma_f32_16x16x32_f16, A-frags read DIRECTLY
// from global wtl (64 KB, L2-resident across all 391 blocks). Deleting the
// 64 KB LDS W-stage: LDS 80->16 KB => 4 blocks/CU (was 2) and no per-block
// staging prologue. 8 independent 16 B a-loads per K-step give the L2-hit
// latency plenty of MFMA overlap.
// ---------------------------------------------------------------------------
#define BM 128
#define GEMM_BLOCKS ((N_NODES + BM - 1) / BM)   // 391

#define CVT16(lo, hi) do { \
    lo[0]=(_Float16)xr[0].x; lo[1]=(_Float16)xr[0].y; lo[2]=(_Float16)xr[0].z; lo[3]=(_Float16)xr[0].w; \
    lo[4]=(_Float16)xr[1].x; lo[5]=(_Float16)xr[1].y; lo[6]=(_Float16)xr[1].z; lo[7]=(_Float16)xr[1].w; \
    hi[0]=(_Float16)xr[2].x; hi[1]=(_Float16)xr[2].y; hi[2]=(_Float16)xr[2].z; hi[3]=(_Float16)xr[2].w; \
    hi[4]=(_Float16)xr[3].x; hi[5]=(_Float16)xr[3].y; hi[6]=(_Float16)xr[3].z; hi[7]=(_Float16)xr[3].w; \
} while (0)

__global__ __launch_bounds__(256, 4) void gemm_xw_mfma(const float* __restrict__ x,
                                                       const __half* __restrict__ wtl,
                                                       __half* __restrict__ h) {
    __shared__ f16x8 xs8[2][4][BM];   // [buf][kg][m] -> 8 halves : 16 KB

    const int t    = threadIdx.x;
    const int lane = t & 63;
    const int wv   = t >> 6;
    const int row0 = blockIdx.x * BM;

    const int srow = t >> 1;
    const int skh  = t & 1;
    const int grow = row0 + srow;
    const bool rv  = grow < N_NODES;
    const float* xp = x + (size_t)(rv ? grow : 0) * IN_DIM + skh * 16;

    float4 xr[4];
#pragma unroll
    for (int i = 0; i < 4; ++i)
        xr[i] = rv ? ((const float4*)xp)[i] : make_float4(0.f, 0.f, 0.f, 0.f);
    {
        f16x8 lo, hi;
        CVT16(lo, hi);
        xs8[0][skh * 2 + 0][srow] = lo;
        xs8[0][skh * 2 + 1][srow] = hi;
    }
    __syncthreads();

    f32x4 acc[2][8];
#pragma unroll
    for (int mf = 0; mf < 2; ++mf)
#pragma unroll
        for (int nf = 0; nf < 8; ++nf) acc[mf][nf] = (f32x4){0.f, 0.f, 0.f, 0.f};

    const int kg  = lane >> 4;
    const int l15 = lane & 15;
    const int mb  = (wv << 5) + l15;
    const f16x8* wp = (const f16x8*)wtl;   // frag-native: [(ks*4+kg)*128 + nf*16 + l15]

#pragma unroll
    for (int ks = 0; ks < 8; ++ks) {
        const int cur = ks & 1;
        if (ks < 7) {
#pragma unroll
            for (int i = 0; i < 4; ++i)
                xr[i] = rv ? ((const float4*)(xp + (ks + 1) * 32))[i]
                           : make_float4(0.f, 0.f, 0.f, 0.f);
        }
        const f16x8 b0 = xs8[cur][kg][mb];
        const f16x8 b1 = xs8[cur][kg][mb + 16];
        const int abase = (((ks << 2) | kg) << 7) + l15;
#pragma unroll
        for (int nf = 0; nf < 8; ++nf) {
            const f16x8 a = wp[abase + (nf << 4)];       // global, L2-hot
            acc[0][nf] = __builtin_amdgcn_mfma_f32_16x16x32_f16(a, b0, acc[0][nf], 0, 0, 0);
            acc[1][nf] = __builtin_amdgcn_mfma_f32_16x16x32_f16(a, b1, acc[1][nf], 0, 0, 0);
        }
        if (ks < 7) {
            f16x8 lo, hi;
            CVT16(lo, hi);
            xs8[cur ^ 1][skh * 2 + 0][srow] = lo;
            xs8[cur ^ 1][skh * 2 + 1][srow] = hi;
            __syncthreads();
        }
    }

    const int rg = lane >> 4;
#pragma unroll
    for (int mf = 0; mf < 2; ++mf) {
        const int m = row0 + (wv << 5) + (mf << 4) + l15;
        if (m < N_NODES) {
            __half* hp = h + (size_t)m * OUT_DIM + (rg << 2);
#pragma unroll
            for (int nf = 0; nf < 8; ++nf) {
                union { ushort4 u; __half f[4]; } o;
                o.f[0] = __float2half(acc[mf][nf][0]);
                o.f[1] = __float2half(acc[mf][nf][1]);
                o.f[2] = __float2half(acc[mf][nf][2]);
                o.f[3] = __float2half(acc[mf][nf][3]);
                *(ushort4*)(hp + (nf << 4)) = o.u;
            }
        }
    }
}

// ---------------------------------------------------------------------------
// Kernel 2 (coarse scatter, deterministic slots). Unchanged from round 7.
// Record: { row<<16 | col , val_bits }.
// ---------------------------------------------------------------------------
__global__ __launch_bounds__(512) void scatter_coarse(const int* __restrict__ rows,
                                                      const int* __restrict__ cols,
                                                      const float* __restrict__ vals,
                                                      int* __restrict__ ccnt,
                                                      int* __restrict__ ovfcnt,
                                                      int2* __restrict__ cbuf,
                                                      int2* __restrict__ ovfbuf,
                                                      const float* __restrict__ w,
                                                      __half* __restrict__ wtl) {
    if (blockIdx.x >= SCAT_BLOCKS) {
        const int e0 = ((blockIdx.x - SCAT_BLOCKS) * 512 + threadIdx.x) * 8;
        const int k  = e0 >> 7;
        const int n0 = e0 & 127;
        const float4 a = *(const float4*)(w + e0);
        const float4 b = *(const float4*)(w + e0 + 4);
        __half* dst = wtl + ((size_t)((k >> 3) * 128 + n0)) * 8 + (k & 7);
        dst[0]  = __float2half(a.x);
        dst[8]  = __float2half(a.y);
        dst[16] = __float2half(a.z);
        dst[24] = __float2half(a.w);
        dst[32] = __float2half(b.x);
        dst[40] = __float2half(b.y);
        dst[48] = __float2half(b.z);
        dst[56] = __float2half(b.w);
        return;
    }

    __shared__ int lcur[NSB];
    const int t = threadIdx.x;
    const int blk = blockIdx.x;
    const int ebase = blk * EPB_S;

    if (t < NSB) lcur[t] = 0;
    __syncthreads();

#pragma unroll
    for (int k = 0; k < SCAT_ITERS; ++k) {
        const int i = k * 512 + t;
        if (i < EPB_S) {
            const int e = ebase + i;
            const int r = rows[e];
            const int sb = r >> SB_SH;
            const int off = atomicAdd(&lcur[sb], 1);     // LDS-private
            const int key = (int)(((unsigned)r << 16) | (unsigned)cols[e]);
            const int vb  = __float_as_int(vals[e]);
            if (off < SEG) {
                cbuf[((size_t)sb * SCAT_BLOCKS + blk) * SEG + off] = make_int2(key, vb);
            } else {
                const int p = atomicAdd(ovfcnt, 1);      // statistically unreachable
                if (p < OVF_CAP) ovfbuf[p] = make_int2(key, vb);
            }
        }
    }
    __syncthreads();

    if (t < NSB) ccnt[t * SCAT_BLOCKS + blk] = min(lcur[t], SEG);
}

// ---------------------------------------------------------------------------
// Kernel 3 (fine scatter, deterministic slots). Unchanged from round 7.
// Fine record: { col | (row & 31) << 16 , val_bits }.
// ---------------------------------------------------------------------------
__global__ __launch_bounds__(512) void scatter_fine(const int* __restrict__ ccnt,
                                                    int* __restrict__ fcnt,
                                                    int* __restrict__ ovfcnt,
                                                    const int2* __restrict__ cbuf,
                                                    int2* __restrict__ ebuf,
                                                    int2* __restrict__ ovfbuf) {
    __shared__ int lcur[32];
    __shared__ int scnt[32];
    const int t    = threadIdx.x;
    const int sb   = blockIdx.x / NPART;
    const int p    = blockIdx.x % NPART;
    const int wv   = t >> 6;
    const int lane = t & 63;

    if (t < 32) {
        lcur[t] = 0;
        scnt[t] = ccnt[sb * SCAT_BLOCKS + p * 32 + t];
    }
    __syncthreads();

    for (int j = 0; j < 4; ++j) {
        const int seg = (wv << 2) + j;
        const int cnt = scnt[seg];
        const size_t sbase = ((size_t)sb * SCAT_BLOCKS + p * 32 + seg) * SEG;
        for (int i = lane; i < cnt; i += 64) {
            const int2 rc = cbuf[sbase + i];
            const unsigned urow = ((unsigned)rc.x) >> 16;
            const int fb = (int)((urow >> BIN_SH) & 31);
            const int off = atomicAdd(&lcur[fb], 1);
            const int key = (rc.x & 0xFFFF) | (int)((urow & (BIN_ROWS - 1)) << 16);
            if (off < SEG) {
                ebuf[(((size_t)sb * 32 + fb) * NPART + p) * SEG + off] = make_int2(key, rc.y);
            } else {
                const int q = atomicAdd(ovfcnt, 1);      // statistically unreachable
                if (q < OVF_CAP) ovfbuf[q] = rc;         // full-row format
            }
        }
    }
    __syncthreads();

    if (t < 32) fcnt[((sb * 32 + t) * NPART) + p] = min(lcur[t], SEG);
}

// ---------------------------------------------------------------------------
// Kernel 4 (FUSED sort+gather): round-7 structure, but the depth-2 gather
// pipeline is now ENFORCED with sched_barrier(0) after each STAGE -- round
// 6/7's VGPR=48 proved the compiler sank the hn loads to their use (live-
// range shortening), silently restoring depth-1. The fence pins the 4
// independent 256 B h-loads ABOVE the FMA block so they stay in flight
// across it (true 8-deep per wave over two stages). Expect VGPR ~100
// (launch_bounds(512,4) caps at 128 -> still 4 waves/SIMD).
// ---------------------------------------------------------------------------
#define NCLS 256

#define STAGE(IT, HV, VV) do {                                                  \
    _Pragma("unroll")                                                           \
    for (int q = 0; q < 4; ++q) {                                               \
        const int idx = beg[q] + ((IT) << 2) + grp;                             \
        const bool vld = idx < end[q];                                          \
        const int2 r = srec[vld ? idx : 0];                                     \
        VV[q] = vld ? __int_as_float(r.y) : 0.f;                                \
        HV[q] = *(const f16x8*)(h + (size_t)(r.x & 0xFFFF) * OUT_DIM + (gl << 3)); \
    }                                                                           \
} while (0)

__global__ __launch_bounds__(512, 4) void sort_gather(const int* __restrict__ fcnt,
                                                      const int* __restrict__ ovfcnt,
                                                      const int2* __restrict__ ebuf,
                                                      const int2* __restrict__ ovfbuf,
                                                      const __half* __restrict__ h,
                                                      float* __restrict__ out) {
    __shared__ int2 srec[CAPB_TOT];        // 13.3 KB sorted records
    __shared__ int  hist[NCLS];
    __shared__ int  pfx[NCLS];
    __shared__ int  rowoff_l[BIN_ROWS + 1];
    __shared__ int  wsum[4];
    __shared__ int  poff[NPART + 1];

    const int t    = threadIdx.x;
    const int bin  = blockIdx.x;
    const int wv   = t >> 6;
    const int lane = t & 63;

    if (t < NCLS) hist[t] = 0;
    if (t == 0) {
        int a = 0;
        poff[0] = 0;
#pragma unroll
        for (int p = 0; p < NPART; ++p) { a += fcnt[bin * NPART + p]; poff[p + 1] = a; }
    }
    __syncthreads();
    const int cnt = poff[NPART];

#define LOCATE(F, PP, II) do {                                                  \
        PP = 0;                                                                 \
        _Pragma("unroll")                                                       \
        for (int j = 1; j < NPART; ++j) PP += ((F) >= poff[j]);                 \
        II = (F) - poff[PP];                                                    \
    } while (0)

    // ---- pass 1: per-(row,octant) histogram ----
    for (int f = t; f < cnt; f += 512) {
        int p, i; LOCATE(f, p, i);
        const int k = ebuf[((size_t)bin * NPART + p) * SEG + i].x;
        atomicAdd(&hist[(((k >> 16) & 31) << 3) | ((k & 0xFFFF) >> 13)], 1);
    }
    __syncthreads();

    // ---- 256-class scan: 4-wave shfl scan + tiny combine ----
    {
        const int v = (t < NCLS) ? hist[t] : 0;
        int s = v;
#pragma unroll
        for (int off = 1; off < 64; off <<= 1) {
            const int u = __shfl_up(s, off);
            if (lane >= off) s += u;
        }
        if (t < NCLS && lane == 63) wsum[wv] = s;
        __syncthreads();
        if (t == 0) {
            int a = 0;
#pragma unroll
            for (int i = 0; i < 4; ++i) { const int c = wsum[i]; wsum[i] = a; a += c; }
        }
        __syncthreads();
        if (t < NCLS) {
            const int incl = s + wsum[wv];
            pfx[t]  = incl;
            hist[t] = incl - v;
        }
    }
    __syncthreads();
    if (t < BIN_ROWS) rowoff_l[t] = t ? pfx[(t << 3) - 1] : 0;
    if (t == BIN_ROWS) rowoff_l[BIN_ROWS] = cnt;
    __syncthreads();

    // ---- pass 2: counting sort (re-read L2-hot ebuf) ----
    for (int f = t; f < cnt; f += 512) {
        int p, i; LOCATE(f, p, i);
        const int2 r = ebuf[((size_t)bin * NPART + p) * SEG + i];
        const int cls = (((r.x >> 16) & 31) << 3) | ((r.x & 0xFFFF) >> 13);
        const int pos = atomicAdd(&hist[cls], 1);
        srec[pos] = r;
    }
    __syncthreads();

    // ---- gather: wave owns 4 rows, depth-2 pipeline (sched_barrier-pinned) ----
    const int grp = lane >> 4;
    const int gl  = lane & 15;
    const int r0  = wv << 2;

    int beg[4], end[4];
#pragma unroll
    for (int q = 0; q < 4; ++q) { beg[q] = rowoff_l[r0 + q]; end[q] = rowoff_l[r0 + q + 1]; }
    int nmax = 0;
#pragma unroll
    for (int q = 0; q < 4; ++q) nmax = max(nmax, end[q] - beg[q]);
    const int iters = (nmax + 3) >> 2;

    f32x8 acc[4];
#pragma unroll
    for (int q = 0; q < 4; ++q) acc[q] = (f32x8){0.f,0.f,0.f,0.f,0.f,0.f,0.f,0.f};

    f16x8 hc[4], hn[4];
    float vc[4], vn[4];
    if (iters > 0) STAGE(0, hc, vc);
    for (int it = 0; it < iters; ++it) {
        if (it + 1 < iters) STAGE(it + 1, hn, vn);
        __builtin_amdgcn_sched_barrier(0);   // pin hn loads ABOVE the FMA block
#pragma unroll
        for (int q = 0; q < 4; ++q)
#pragma unroll
            for (int j = 0; j < 8; ++j) acc[q][j] += vc[q] * (float)hc[q][j];
        __builtin_amdgcn_sched_barrier(0);   // keep FMA block from swallowing the swap
#pragma unroll
        for (int q = 0; q < 4; ++q) { hc[q] = hn[q]; vc[q] = vn[q]; }
    }

    // ---- overflow replay (0 in practice) ----
    int novf = *ovfcnt;
    if (novf > OVF_CAP) novf = OVF_CAP;
    for (int e = 0; e < novf; ++e) {
        const int2 rec = ovfbuf[e];
        const unsigned urow = ((unsigned)rec.x) >> 16;
        if ((int)(urow >> BIN_SH) == bin && grp == 0) {
            const int lr = (int)(urow & (BIN_ROWS - 1)) - r0;
            if (lr >= 0 && lr < 4) {
                const float v = __int_as_float(rec.y);
                const f16x8 hv = *(const f16x8*)(h + (size_t)(rec.x & 0xFFFF) * OUT_DIM + (gl << 3));
#pragma unroll
                for (int q = 0; q < 4; ++q)
                    if (q == lr)
#pragma unroll
                        for (int j = 0; j < 8; ++j) acc[q][j] += v * (float)hv[j];
            }
        }
    }

    // ---- reduce across the 4 edge-slot groups ----
#pragma unroll
    for (int q = 0; q < 4; ++q)
#pragma unroll
        for (int j = 0; j < 8; ++j) {
            float x = acc[q][j];
            x += __shfl_xor(x, 16);
            x += __shfl_xor(x, 32);
            acc[q][j] = x;
        }

    float res[8];
#pragma unroll
    for (int j = 0; j < 8; ++j) {
        float x = acc[0][j];
        x = (grp == 1) ? acc[1][j] : x;
        x = (grp == 2) ? acc[2][j] : x;
        x = (grp == 3) ? acc[3][j] : x;
        res[j] = lrelu(x);
    }
    const int grow = (bin << BIN_SH) + r0 + grp;
    if (grow < N_NODES) {
        float* op = out + (size_t)grow * OUT_DIM + (gl << 3);
        *(float4*)op       = make_float4(res[0], res[1], res[2], res[3]);
        *(float4*)(op + 4) = make_float4(res[4], res[5], res[6], res[7]);
    }
}

// ---------------------------------------------------------------------------
// Launch: memset(4B) -> coarse(+convW) -> fine -> gemm -> sort_gather.
// cbuf dead after fine, so h ALIASES it.
// ---------------------------------------------------------------------------
extern "C" void kernel_launch(void* const* d_in, const int* in_sizes, int n_in,
                              void* d_out, int out_size, void* d_ws, size_t ws_size,
                              hipStream_t stream) {
    const float* x    = (const float*)d_in[0];
    const float* w    = (const float*)d_in[1];
    const float* vals = (const float*)d_in[2];
    const int*   rows = (const int*)d_in[3];
    const int*   cols = (const int*)d_in[4];
    float* out = (float*)d_out;

    char* ws = (char*)d_ws;
    size_t off = 0;
    auto alloc = [&](size_t bytes) {
        void* p = ws + off;
        off = (off + bytes + 255) & ~(size_t)255;
        return p;
    };
    int2*  cbuf    = (int2*) alloc((size_t)NSB * SCAT_BLOCKS * SEG * sizeof(int2)); // 20.9 MB
    __half* h      = (__half*)cbuf;   // alias: h (12.8 MB) reuses dead cbuf
    int2*  ebuf    = (int2*) alloc((size_t)NBIN_PAD * NPART * SEG * sizeof(int2));  // 20.9 MB
    int2*  ovfbuf  = (int2*) alloc((size_t)OVF_CAP * sizeof(int2));                 // 0.5 MB
    __half* wtl    = (__half*)alloc((size_t)IN_DIM * OUT_DIM * sizeof(__half));     // 64 KB
    int*   ccnt    = (int*)  alloc((size_t)NSB * SCAT_BLOCKS * sizeof(int));        // 50 KB
    int*   fcnt    = (int*)  alloc((size_t)NBIN_PAD * NPART * sizeof(int));         // 50 KB
    int*   ovfcnt  = (int*)  alloc(sizeof(int));

    hipMemsetAsync(ovfcnt, 0, sizeof(int), stream);

    scatter_coarse<<<SCAT_BLOCKS + CONVW_BLOCKS, 512, 0, stream>>>(rows, cols, vals,
                                                                   ccnt, ovfcnt, cbuf, ovfbuf, w, wtl);
    scatter_fine<<<NSB * NPART, 512, 0, stream>>>(ccnt, fcnt, ovfcnt, cbuf, ebuf, ovfbuf);
    gemm_xw_mfma<<<GEMM_BLOCKS, 256, 0, stream>>>(x, wtl, h);
    sort_gather<<<NBIN, 512, 0, stream>>>(fcnt, ovfcnt, ebuf, ovfbuf, h, out);
}

// Round 9
// 203.813 us; speedup vs baseline: 1.0048x; 1.0048x over previous
//
#include <hip/hip_runtime.h>
#include <hip/hip_fp16.h>

#define N_NODES 50000
#define N_EDGES 1600000
#define IN_DIM 256
#define OUT_DIM 128
#define NEG_SLOPE 0.01f

// ---- two-level scatter, deterministic slots (ZERO global atomics) ----
#define SB_SH     10
#define SB_ROWS   1024
#define NSB       ((N_NODES + SB_ROWS - 1) / SB_ROWS)   // 49
#define SEG       208                                   // records per segment (+7 sigma)

#define BIN_SH    5
#define BIN_ROWS  32
#define NBIN      ((N_NODES + BIN_ROWS - 1) / BIN_ROWS) // 1563
#define NBIN_PAD  (NSB * 32)                            // 1568
#define NPART     8                                     // fine parts per super-bin
#define CAPB_TOT  (NPART * SEG)                         // 1664 max records/bin
#define OVF_CAP   65536

#define SCAT_BLOCKS 256
#define CONVW_BLOCKS 8
#define EPB_S (N_EDGES / SCAT_BLOCKS)    // 6250
#define SCAT_ITERS ((EPB_S + 511) / 512) // 13

typedef _Float16 f16x8 __attribute__((ext_vector_type(8)));
typedef float    f32x4 __attribute__((ext_vector_type(4)));
typedef float    f32x8 __attribute__((ext_vector_type(8)));

__device__ __forceinline__ float lrelu(float v) {
    return v >= 0.f ? v : NEG_SLOPE * v;
}

// ---------------------------------------------------------------------------
// Kernel 1: h = x @ W via v_mfma_f32_16x16x32_f16 (round-7 LDS version;
// round-8's global-W A-loads regressed ~6 us -- L2-latency-serial in the
// MFMA loop. Reverted.)
// ---------------------------------------------------------------------------
#define BM 128
#define GEMM_BLOCKS ((N_NODES + BM - 1) / BM)   // 391

#define CVT16(lo, hi) do { \
    lo[0]=(_Float16)xr[0].x; lo[1]=(_Float16)xr[0].y; lo[2]=(_Float16)xr[0].z; lo[3]=(_Float16)xr[0].w; \
    lo[4]=(_Float16)xr[1].x; lo[5]=(_Float16)xr[1].y; lo[6]=(_Float16)xr[1].z; lo[7]=(_Float16)xr[1].w; \
    hi[0]=(_Float16)xr[2].x; hi[1]=(_Float16)xr[2].y; hi[2]=(_Float16)xr[2].z; hi[3]=(_Float16)xr[2].w; \
    hi[4]=(_Float16)xr[3].x; hi[5]=(_Float16)xr[3].y; hi[6]=(_Float16)xr[3].z; hi[7]=(_Float16)xr[3].w; \
} while (0)

__global__ __launch_bounds__(256, 2) void gemm_xw_mfma(const float* __restrict__ x,
                                                       const __half* __restrict__ wtl,
                                                       __half* __restrict__ h) {
    __shared__ f16x8 wt8[32 * 128];   // 64 KB whole-W frag-native
    __shared__ f16x8 xs8[2][4][BM];   // 16 KB double-buffered K-steps

    const int t    = threadIdx.x;
    const int lane = t & 63;
    const int wv   = t >> 6;
    const int row0 = blockIdx.x * BM;

    {
        const int4* src = (const int4*)wtl;
        int4* dst = (int4*)wt8;
#pragma unroll
        for (int i = 0; i < 16; ++i) dst[i * 256 + t] = src[i * 256 + t];
    }

    const int srow = t >> 1;
    const int skh  = t & 1;
    const int grow = row0 + srow;
    const bool rv  = grow < N_NODES;
    const float* xp = x + (size_t)(rv ? grow : 0) * IN_DIM + skh * 16;

    float4 xr[4];
#pragma unroll
    for (int i = 0; i < 4; ++i)
        xr[i] = rv ? ((const float4*)xp)[i] : make_float4(0.f, 0.f, 0.f, 0.f);
    {
        f16x8 lo, hi;
        CVT16(lo, hi);
        xs8[0][skh * 2 + 0][srow] = lo;
        xs8[0][skh * 2 + 1][srow] = hi;
    }
    __syncthreads();

    f32x4 acc[2][8];
#pragma unroll
    for (int mf = 0; mf < 2; ++mf)
#pragma unroll
        for (int nf = 0; nf < 8; ++nf) acc[mf][nf] = (f32x4){0.f, 0.f, 0.f, 0.f};

    const int kg  = lane >> 4;
    const int l15 = lane & 15;
    const int mb  = (wv << 5) + l15;

#pragma unroll
    for (int ks = 0; ks < 8; ++ks) {
        const int cur = ks & 1;
        if (ks < 7) {
#pragma unroll
            for (int i = 0; i < 4; ++i)
                xr[i] = rv ? ((const float4*)(xp + (ks + 1) * 32))[i]
                           : make_float4(0.f, 0.f, 0.f, 0.f);
        }
        const f16x8 b0 = xs8[cur][kg][mb];
        const f16x8 b1 = xs8[cur][kg][mb + 16];
#pragma unroll
        for (int nf = 0; nf < 8; ++nf) {
            const f16x8 a = wt8[(((ks << 2) | kg) << 7) + (nf << 4) + l15];
            acc[0][nf] = __builtin_amdgcn_mfma_f32_16x16x32_f16(a, b0, acc[0][nf], 0, 0, 0);
            acc[1][nf] = __builtin_amdgcn_mfma_f32_16x16x32_f16(a, b1, acc[1][nf], 0, 0, 0);
        }
        if (ks < 7) {
            f16x8 lo, hi;
            CVT16(lo, hi);
            xs8[cur ^ 1][skh * 2 + 0][srow] = lo;
            xs8[cur ^ 1][skh * 2 + 1][srow] = hi;
            __syncthreads();
        }
    }

    const int rg = lane >> 4;
#pragma unroll
    for (int mf = 0; mf < 2; ++mf) {
        const int m = row0 + (wv << 5) + (mf << 4) + l15;
        if (m < N_NODES) {
            __half* hp = h + (size_t)m * OUT_DIM + (rg << 2);
#pragma unroll
            for (int nf = 0; nf < 8; ++nf) {
                union { ushort4 u; __half f[4]; } o;
                o.f[0] = __float2half(acc[mf][nf][0]);
                o.f[1] = __float2half(acc[mf][nf][1]);
                o.f[2] = __float2half(acc[mf][nf][2]);
                o.f[3] = __float2half(acc[mf][nf][3]);
                *(ushort4*)(hp + (nf << 4)) = o.u;
            }
        }
    }
}

// ---------------------------------------------------------------------------
// Kernel 2 (coarse scatter, LDS-SORTED + COALESCED WRITES): the round-7/8
// version's 8 B stores went to ~30+ distinct segments per wave-instruction
// (cursor-dependent addressing) -> multi-transaction scatter, est. ~50 us.
// Now: LDS counting sort of the block's 6250 records by super-bin (50 KB),
// then flat write -- consecutive lanes hit consecutive addresses of the
// same segment. Record: { row<<16 | col , val_bits }.
// ---------------------------------------------------------------------------
__global__ __launch_bounds__(512) void scatter_coarse(const int* __restrict__ rows,
                                                      const int* __restrict__ cols,
                                                      const float* __restrict__ vals,
                                                      int* __restrict__ ccnt,
                                                      int* __restrict__ ovfcnt,
                                                      int2* __restrict__ cbuf,
                                                      int2* __restrict__ ovfbuf,
                                                      const float* __restrict__ w,
                                                      __half* __restrict__ wtl) {
    if (blockIdx.x >= SCAT_BLOCKS) {
        const int e0 = ((blockIdx.x - SCAT_BLOCKS) * 512 + threadIdx.x) * 8;
        const int k  = e0 >> 7;
        const int n0 = e0 & 127;
        const float4 a = *(const float4*)(w + e0);
        const float4 b = *(const float4*)(w + e0 + 4);
        __half* dst = wtl + ((size_t)((k >> 3) * 128 + n0)) * 8 + (k & 7);
        dst[0]  = __float2half(a.x);
        dst[8]  = __float2half(a.y);
        dst[16] = __float2half(a.z);
        dst[24] = __float2half(a.w);
        dst[32] = __float2half(b.x);
        dst[40] = __float2half(b.y);
        dst[48] = __float2half(b.z);
        dst[56] = __float2half(b.w);
        return;
    }

    __shared__ int2 lsort[EPB_S];          // 50 KB sorted-by-sbin records
    __shared__ int  hist[NSB];             // count -> cursor -> inclusive end
    __shared__ int  cstart[NSB];

    const int t    = threadIdx.x;
    const int lane = t & 63;
    const int blk  = blockIdx.x;
    const int ebase = blk * EPB_S;

    if (t < NSB) hist[t] = 0;
    __syncthreads();

    // pass 1: histogram by sbin (rows cached in regs)
    int myr[SCAT_ITERS];
#pragma unroll
    for (int k = 0; k < SCAT_ITERS; ++k) {
        const int i = k * 512 + t;
        myr[k] = -1;
        if (i < EPB_S) {
            myr[k] = rows[ebase + i];
            atomicAdd(&hist[myr[k] >> SB_SH], 1);
        }
    }
    __syncthreads();

    // exclusive scan over 49 sbins (wave 0)
    if (t < 64) {
        const int v = (t < NSB) ? hist[t] : 0;
        int s = v;
#pragma unroll
        for (int off = 1; off < 64; off <<= 1) {
            const int u = __shfl_up(s, off);
            if (lane >= off) s += u;
        }
        if (t < NSB) { cstart[t] = s - v; hist[t] = s - v; }   // hist = cursor
    }
    __syncthreads();

    // pass 2: place into LDS sorted order (cols/vals read coalesced)
#pragma unroll
    for (int k = 0; k < SCAT_ITERS; ++k) {
        const int i = k * 512 + t;
        if (i < EPB_S) {
            const int e = ebase + i;
            const int r = myr[k];
            const int pos = atomicAdd(&hist[r >> SB_SH], 1);
            lsort[pos] = make_int2((int)(((unsigned)r << 16) | (unsigned)cols[e]),
                                   __float_as_int(vals[e]));
        }
    }
    __syncthreads();

    // pass 3: flat coalesced write-out (sbin recovered from the record)
    for (int i = t; i < EPB_S; i += 512) {
        const int2 rc = lsort[i];
        const int sb  = (int)(((unsigned)rc.x) >> 16) >> SB_SH;
        const int off = i - cstart[sb];
        if (off < SEG) {
            cbuf[((size_t)sb * SCAT_BLOCKS + blk) * SEG + off] = rc;
        } else {
            const int p = atomicAdd(ovfcnt, 1);          // statistically unreachable
            if (p < OVF_CAP) ovfbuf[p] = rc;
        }
    }
    __syncthreads();

    if (t < NSB) ccnt[t * SCAT_BLOCKS + blk] = min(hist[t] - cstart[t], SEG);
}

// ---------------------------------------------------------------------------
// Kernel 3 (fine scatter, LDS-SORTED + COALESCED WRITES): block (sbin,part)
// reads its 32 L2-hot source segments twice (hist, then place into 53 KB
// LDS sorted by fine bin), then writes flat -- coalesced. The fine-bin id
// rides in bits 21..25 of the key (gather masks them out).
// Fine record: { col | (row&31)<<16 | fb<<21 , val_bits }.
// ---------------------------------------------------------------------------
__global__ __launch_bounds__(512) void scatter_fine(const int* __restrict__ ccnt,
                                                    int* __restrict__ fcnt,
                                                    int* __restrict__ ovfcnt,
                                                    const int2* __restrict__ cbuf,
                                                    int2* __restrict__ ebuf,
                                                    int2* __restrict__ ovfbuf) {
    __shared__ int2 lsort[32 * SEG];       // 53 KB
    __shared__ int  hist[32];
    __shared__ int  cstart[32];
    __shared__ int  scnt[32];
    __shared__ int  stot;

    const int t    = threadIdx.x;
    const int lane = t & 63;
    const int wv   = t >> 6;
    const int sb   = blockIdx.x / NPART;
    const int p    = blockIdx.x % NPART;

    if (t < 32) {
        hist[t] = 0;
        scnt[t] = ccnt[sb * SCAT_BLOCKS + p * 32 + t];
    }
    __syncthreads();

    // pass 1: histogram by fine bin (each wave owns 4 source segments)
    for (int j = 0; j < 4; ++j) {
        const int seg = (wv << 2) + j;
        const int cnt = scnt[seg];
        const size_t sbase = ((size_t)sb * SCAT_BLOCKS + p * 32 + seg) * SEG;
        for (int i = lane; i < cnt; i += 64)
            atomicAdd(&hist[(cbuf[sbase + i].x >> 21) & 31], 1);
    }
    __syncthreads();

    // exclusive scan over 32 fine bins (wave 0)
    if (t < 32) {
        const int v = hist[t];
        int s = v;
#pragma unroll
        for (int off = 1; off < 32; off <<= 1) {
            const int u = __shfl_up(s, off);
            if (t >= off) s += u;
        }
        if (t == 31) stot = s;
        cstart[t] = s - v;
        hist[t]   = s - v;                 // cursor
    }
    __syncthreads();

    // pass 2: place into LDS sorted by fine bin (cbuf re-read, L2-hot)
    for (int j = 0; j < 4; ++j) {
        const int seg = (wv << 2) + j;
        const int cnt = scnt[seg];
        const size_t sbase = ((size_t)sb * SCAT_BLOCKS + p * 32 + seg) * SEG;
        for (int i = lane; i < cnt; i += 64) {
            const int2 rc = cbuf[sbase + i];
            const unsigned urow = ((unsigned)rc.x) >> 16;
            const int fb = (int)((urow >> BIN_SH) & 31);
            const int pos = atomicAdd(&hist[fb], 1);
            lsort[pos] = make_int2((rc.x & 0xFFFF) | (int)((urow & (BIN_ROWS - 1)) << 16)
                                                   | (fb << 21), rc.y);
        }
    }
    __syncthreads();

    // pass 3: flat coalesced write-out
    const int tot = stot;
    for (int i = t; i < tot; i += 512) {
        const int2 rc = lsort[i];
        const int fb  = (rc.x >> 21) & 31;
        const int off = i - cstart[fb];
        if (off < SEG) {
            ebuf[(((size_t)sb * 32 + fb) * NPART + p) * SEG + off] = rc;
        } else {
            const int q = atomicAdd(ovfcnt, 1);          // statistically unreachable
            if (q < OVF_CAP) {
                const int row = (sb << SB_SH) | (fb << BIN_SH) | ((rc.x >> 16) & 31);
                ovfbuf[q] = make_int2((int)(((unsigned)row << 16) | (unsigned)(rc.x & 0xFFFF)), rc.y);
            }
        }
    }
    __syncthreads();

    if (t < 32) fcnt[((sb * 32 + t) * NPART) + p] = min(hist[t] - cstart[t], SEG);
}

// ---------------------------------------------------------------------------
// Kernel 4 (FUSED sort+gather): single ebuf read (staged to urec; round 7's
// double-read + LOCATE dropped), then LDS->LDS counting sort by (row,octant),
// then the depth-2 gather pipeline with UNCONDITIONAL clamped STAGE --
// rounds 5-8's pipeline was silently folded because the loads sat in a
// guarded basic block where sched_barrier couldn't pin them (VGPR stuck at
// 48 = proof). Now loads are in the loop's single BB; sched_barrier(0)
// fences them above the FMA block. Expect VGPR ~100; verify in counters.
// ---------------------------------------------------------------------------
#define NCLS 256

#define STAGE(IT, HV, VV) do {                                                  \
    _Pragma("unroll")                                                           \
    for (int q = 0; q < 4; ++q) {                                               \
        const int idx = beg[q] + ((IT) << 2) + grp;                             \
        const bool vld = idx < end[q];                                          \
        const int2 r = srec[vld ? idx : last];                                  \
        VV[q] = vld ? __int_as_float(r.y) : 0.f;                                \
        HV[q] = *(const f16x8*)(h + (size_t)(r.x & 0xFFFF) * OUT_DIM + (gl << 3)); \
    }                                                                           \
} while (0)

__global__ __launch_bounds__(512, 4) void sort_gather(const int* __restrict__ fcnt,
                                                      const int* __restrict__ ovfcnt,
                                                      const int2* __restrict__ ebuf,
                                                      const int2* __restrict__ ovfbuf,
                                                      const __half* __restrict__ h,
                                                      float* __restrict__ out) {
    __shared__ int2 urec[CAPB_TOT];        // 13.3 KB raw staged records
    __shared__ int2 srec[CAPB_TOT];        // 13.3 KB sorted records
    __shared__ int  hist[NCLS];
    __shared__ int  pfx[NCLS];
    __shared__ int  rowoff_l[BIN_ROWS + 1];
    __shared__ int  wsum[4];
    __shared__ int  poff[NPART + 1];

    const int t    = threadIdx.x;
    const int bin  = blockIdx.x;
    const int wv   = t >> 6;
    const int lane = t & 63;

    if (t < NCLS) hist[t] = 0;
    if (t == 0) {
        int a = 0;
        poff[0] = 0;
#pragma unroll
        for (int p = 0; p < NPART; ++p) { a += fcnt[bin * NPART + p]; poff[p + 1] = a; }
    }
    __syncthreads();
    const int cnt = poff[NPART];

    // ---- pass 1: stage part wv to urec (single ebuf read) + histogram ----
    {
        const int cp = poff[wv + 1] - poff[wv];
        const size_t pb = ((size_t)bin * NPART + wv) * SEG;
        const int ub = poff[wv];
        for (int i = lane; i < cp; i += 64) {
            const int2 r = ebuf[pb + i];
            urec[ub + i] = r;
            atomicAdd(&hist[(((r.x >> 16) & 31) << 3) | ((r.x & 0xFFFF) >> 13)], 1);
        }
    }
    __syncthreads();

    // ---- 256-class scan: 4-wave shfl scan + tiny combine ----
    {
        const int v = (t < NCLS) ? hist[t] : 0;
        int s = v;
#pragma unroll
        for (int off = 1; off < 64; off <<= 1) {
            const int u = __shfl_up(s, off);
            if (lane >= off) s += u;
        }
        if (t < NCLS && lane == 63) wsum[wv] = s;
        __syncthreads();
        if (t == 0) {
            int a = 0;
#pragma unroll
            for (int i = 0; i < 4; ++i) { const int c = wsum[i]; wsum[i] = a; a += c; }
        }
        __syncthreads();
        if (t < NCLS) {
            const int incl = s + wsum[wv];
            pfx[t]  = incl;
            hist[t] = incl - v;
        }
    }
    __syncthreads();
    if (t < BIN_ROWS) rowoff_l[t] = t ? pfx[(t << 3) - 1] : 0;
    if (t == BIN_ROWS) rowoff_l[BIN_ROWS] = cnt;
    __syncthreads();

    // ---- pass 2: counting sort LDS -> LDS ----
    for (int i = t; i < cnt; i += 512) {
        const int2 r = urec[i];
        const int cls = (((r.x >> 16) & 31) << 3) | ((r.x & 0xFFFF) >> 13);
        const int pos = atomicAdd(&hist[cls], 1);
        srec[pos] = r;
    }
    __syncthreads();

    // ---- gather: wave owns 4 rows, TRUE depth-2 pipeline ----
    const int grp = lane >> 4;
    const int gl  = lane & 15;
    const int r0  = wv << 2;
    const int last = cnt > 0 ? cnt - 1 : 0;

    int beg[4], end[4];
#pragma unroll
    for (int q = 0; q < 4; ++q) { beg[q] = rowoff_l[r0 + q]; end[q] = rowoff_l[r0 + q + 1]; }
    int nmax = 0;
#pragma unroll
    for (int q = 0; q < 4; ++q) nmax = max(nmax, end[q] - beg[q]);
    const int iters = (nmax + 3) >> 2;

    f32x8 acc[4];
#pragma unroll
    for (int q = 0; q < 4; ++q) acc[q] = (f32x8){0.f,0.f,0.f,0.f,0.f,0.f,0.f,0.f};

    if (cnt > 0 && iters > 0) {
        f16x8 hc[4], hn[4];
        float vc[4], vn[4];
        STAGE(0, hc, vc);
        for (int it = 0; it < iters; ++it) {
            const int itn = (it + 1 < iters) ? it + 1 : it;   // clamped: UNCONDITIONAL loads
            STAGE(itn, hn, vn);
            __builtin_amdgcn_sched_barrier(0);   // loads pinned above the FMA block
#pragma unroll
            for (int q = 0; q < 4; ++q)
#pragma unroll
                for (int j = 0; j < 8; ++j) acc[q][j] += vc[q] * (float)hc[q][j];
            __builtin_amdgcn_sched_barrier(0);
#pragma unroll
            for (int q = 0; q < 4; ++q) { hc[q] = hn[q]; vc[q] = vn[q]; }
        }
    }

    // ---- overflow replay (0 in practice) ----
    int novf = *ovfcnt;
    if (novf > OVF_CAP) novf = OVF_CAP;
    for (int e = 0; e < novf; ++e) {
        const int2 rec = ovfbuf[e];
        const unsigned urow = ((unsigned)rec.x) >> 16;
        if ((int)(urow >> BIN_SH) == bin && grp == 0) {
            const int lr = (int)(urow & (BIN_ROWS - 1)) - r0;
            if (lr >= 0 && lr < 4) {
                const float v = __int_as_float(rec.y);
                const f16x8 hv = *(const f16x8*)(h + (size_t)(rec.x & 0xFFFF) * OUT_DIM + (gl << 3));
#pragma unroll
                for (int q = 0; q < 4; ++q)
                    if (q == lr)
#pragma unroll
                        for (int j = 0; j < 8; ++j) acc[q][j] += v * (float)hv[j];
            }
        }
    }

    // ---- reduce across the 4 edge-slot groups ----
#pragma unroll
    for (int q = 0; q < 4; ++q)
#pragma unroll
        for (int j = 0; j < 8; ++j) {
            float x = acc[q][j];
            x += __shfl_xor(x, 16);
            x += __shfl_xor(x, 32);
            acc[q][j] = x;
        }

    float res[8];
#pragma unroll
    for (int j = 0; j < 8; ++j) {
        float x = acc[0][j];
        x = (grp == 1) ? acc[1][j] : x;
        x = (grp == 2) ? acc[2][j] : x;
        x = (grp == 3) ? acc[3][j] : x;
        res[j] = lrelu(x);
    }
    const int grow = (bin << BIN_SH) + r0 + grp;
    if (grow < N_NODES) {
        float* op = out + (size_t)grow * OUT_DIM + (gl << 3);
        *(float4*)op       = make_float4(res[0], res[1], res[2], res[3]);
        *(float4*)(op + 4) = make_float4(res[4], res[5], res[6], res[7]);
    }
}

// ---------------------------------------------------------------------------
// Launch: memset(4B) -> coarse(+convW) -> fine -> gemm -> sort_gather.
// cbuf dead after fine, so h ALIASES it.
// ---------------------------------------------------------------------------
extern "C" void kernel_launch(void* const* d_in, const int* in_sizes, int n_in,
                              void* d_out, int out_size, void* d_ws, size_t ws_size,
                              hipStream_t stream) {
    const float* x    = (const float*)d_in[0];
    const float* w    = (const float*)d_in[1];
    const float* vals = (const float*)d_in[2];
    const int*   rows = (const int*)d_in[3];
    const int*   cols = (const int*)d_in[4];
    float* out = (float*)d_out;

    char* ws = (char*)d_ws;
    size_t off = 0;
    auto alloc = [&](size_t bytes) {
        void* p = ws + off;
        off = (off + bytes + 255) & ~(size_t)255;
        return p;
    };
    int2*  cbuf    = (int2*) alloc((size_t)NSB * SCAT_BLOCKS * SEG * sizeof(int2)); // 20.9 MB
    __half* h      = (__half*)cbuf;   // alias: h (12.8 MB) reuses dead cbuf
    int2*  ebuf    = (int2*) alloc((size_t)NBIN_PAD * NPART * SEG * sizeof(int2));  // 20.9 MB
    int2*  ovfbuf  = (int2*) alloc((size_t)OVF_CAP * sizeof(int2));                 // 0.5 MB
    __half* wtl    = (__half*)alloc((size_t)IN_DIM * OUT_DIM * sizeof(__half));     // 64 KB
    int*   ccnt    = (int*)  alloc((size_t)NSB * SCAT_BLOCKS * sizeof(int));        // 50 KB
    int*   fcnt    = (int*)  alloc((size_t)NBIN_PAD * NPART * sizeof(int));         // 50 KB
    int*   ovfcnt  = (int*)  alloc(sizeof(int));

    hipMemsetAsync(ovfcnt, 0, sizeof(int), stream);

    scatter_coarse<<<SCAT_BLOCKS + CONVW_BLOCKS, 512, 0, stream>>>(rows, cols, vals,
                                                                   ccnt, ovfcnt, cbuf, ovfbuf, w, wtl);
    scatter_fine<<<NSB * NPART, 512, 0, stream>>>(ccnt, fcnt, ovfcnt, cbuf, ebuf, ovfbuf);
    gemm_xw_mfma<<<GEMM_BLOCKS, 256, 0, stream>>>(x, wtl, h);
    sort_gather<<<NBIN, 512, 0, stream>>>(fcnt, ovfcnt, ebuf, ovfbuf, h, out);
}

// Round 10
// 202.734 us; speedup vs baseline: 1.0102x; 1.0053x over previous
//
#include <hip/hip_runtime.h>
#include <hip/hip_fp16.h>

#define N_NODES 50000
#define N_EDGES 1600000
#define IN_DIM 256
#define OUT_DIM 128
#define NEG_SLOPE 0.01f

// ---- geometry ----
#define SB_SH     10
#define NSB       49                       // super-bins of 1024 rows
#define BIN_SH    5
#define BIN_ROWS  32
#define NBIN_PAD  (NSB * 32)               // 1568 fine bins (incl. 5 empty)
#define NPART     8                        // fine parts per super-bin
#define ECAP      4608                     // records per (sb,part) dense slab (+8 sigma)
#define SEGP      256                      // per-(bin,part) staged cap in gather (+11 sigma)
#define CAPG      (NPART * SEGP)           // 2048 gather LDS records
#define OVF_CAP   65536

#define SCAT_BLOCKS 256
#define EPB_S (N_EDGES / SCAT_BLOCKS)      // 6250
#define SCAT_ITERS ((EPB_S + 511) / 512)   // 13

#define BM 128
#define GEMM_BLOCKS ((N_NODES + BM - 1) / BM)  // 391
#define PREP_BLOCKS (SCAT_BLOCKS + GEMM_BLOCKS + 1)

typedef _Float16 f16x8 __attribute__((ext_vector_type(8)));
typedef float    f32x4 __attribute__((ext_vector_type(4)));
typedef float    f32x8 __attribute__((ext_vector_type(8)));

__device__ __forceinline__ float lrelu(float v) {
    return v >= 0.f ? v : NEG_SLOPE * v;
}

#define CVT16(lo, hi) do { \
    lo[0]=(_Float16)xr[0].x; lo[1]=(_Float16)xr[0].y; lo[2]=(_Float16)xr[0].z; lo[3]=(_Float16)xr[0].w; \
    lo[4]=(_Float16)xr[1].x; lo[5]=(_Float16)xr[1].y; lo[6]=(_Float16)xr[1].z; lo[7]=(_Float16)xr[1].w; \
    hi[0]=(_Float16)xr[2].x; hi[1]=(_Float16)xr[2].y; hi[2]=(_Float16)xr[2].z; hi[3]=(_Float16)xr[2].w; \
    hi[4]=(_Float16)xr[3].x; hi[5]=(_Float16)xr[3].y; hi[6]=(_Float16)xr[3].z; hi[7]=(_Float16)xr[3].w; \
} while (0)

// ---------------------------------------------------------------------------
// Dispatch 1 "prep" (648 blocks, 512 thr, 50.4 KB smem union):
//   blocks 0..255   : coarse scatter -- LDS counting sort by super-bin, then
//                     DENSE per-block write (cbuf[blk*6250+i], 100% coalesced;
//                     per-block cstart table replaces fixed SEG slots).
//   blocks 256..646 : gemm h = x@W -- stages W fp32->f16 frag layout itself
//                     in two 32 KB halves (no wtl dependency), 256 active
//                     threads, all 512 participate in barriers.
//   block  647      : zeroes ovfcnt (replaces the memset dispatch).
// gemm runs CONCURRENTLY with the coarse scatter (independent data).
// ---------------------------------------------------------------------------
__global__ __launch_bounds__(512, 2) void prep(const int* __restrict__ rows,
                                               const int* __restrict__ cols,
                                               const float* __restrict__ vals,
                                               const float* __restrict__ x,
                                               const float* __restrict__ w,
                                               int* __restrict__ cstartarr,
                                               int* __restrict__ ovfcnt,
                                               int2* __restrict__ cbuf,
                                               __half* __restrict__ h) {
    __shared__ __attribute__((aligned(16))) char smem[50432];
    const int bid = blockIdx.x;
    const int t   = threadIdx.x;

    if (bid >= SCAT_BLOCKS + GEMM_BLOCKS) {        // zero-block
        if (t == 0) *ovfcnt = 0;
        return;
    }

    if (bid < SCAT_BLOCKS) {
        // ================= coarse scatter role =================
        int2* lsort  = (int2*)smem;                // 6250 rec = 50,000 B
        int*  hist   = (int*)(smem + 50000);       // 49
        int*  cstart = (int*)(smem + 50200);       // 49
        const int lane  = t & 63;
        const int blk   = bid;
        const int ebase = blk * EPB_S;

        if (t < NSB) hist[t] = 0;
        __syncthreads();

        int myr[SCAT_ITERS];
#pragma unroll
        for (int k = 0; k < SCAT_ITERS; ++k) {
            const int i = k * 512 + t;
            myr[k] = -1;
            if (i < EPB_S) {
                myr[k] = rows[ebase + i];
                atomicAdd(&hist[myr[k] >> SB_SH], 1);
            }
        }
        __syncthreads();

        if (t < 64) {                              // scan 49 sbins (wave 0)
            const int v = (t < NSB) ? hist[t] : 0;
            int s = v;
#pragma unroll
            for (int off = 1; off < 64; off <<= 1) {
                const int u = __shfl_up(s, off);
                if (lane >= off) s += u;
            }
            if (t < NSB) { cstart[t] = s - v; hist[t] = s - v; }
        }
        __syncthreads();

#pragma unroll
        for (int k = 0; k < SCAT_ITERS; ++k) {
            const int i = k * 512 + t;
            if (i < EPB_S) {
                const int e = ebase + i;
                const int r = myr[k];
                const int pos = atomicAdd(&hist[r >> SB_SH], 1);
                lsort[pos] = make_int2((int)(((unsigned)r << 16) | (unsigned)cols[e]),
                                       __float_as_int(vals[e]));
            }
        }
        __syncthreads();

        // dense coalesced write-out (int4 = 2 records/lane)
        {
            const int4* src = (const int4*)lsort;
            int4* dst = (int4*)(cbuf + (size_t)blk * EPB_S);
            for (int i = t; i < EPB_S / 2; i += 512) dst[i] = src[i];
        }
        if (t < NSB)  cstartarr[blk * 50 + t]   = cstart[t];
        if (t == NSB) cstartarr[blk * 50 + NSB] = EPB_S;
        return;
    }

    // ================= gemm role (t<256 active) =================
    f16x8* wt8h = (f16x8*)smem;                    // [kgi_local 0..15][n 0..127] : 32 KB
    f16x8* xs8  = (f16x8*)(smem + 32768);          // [(buf*4+kg)*128+m]          : 16 KB
    const int a256 = (t < 256);
    const int lane = t & 63;
    const int wv   = t >> 6;
    const int row0 = (bid - SCAT_BLOCKS) * BM;

    const int srow = t >> 1;
    const int skh  = t & 1;
    const int grow = row0 + srow;
    const bool rv  = a256 && (grow < N_NODES);
    const float* xp = x + (size_t)(rv ? grow : 0) * IN_DIM + skh * 16;

    float4 xr[4];
    if (a256) {
#pragma unroll
        for (int i = 0; i < 4; ++i)
            xr[i] = rv ? ((const float4*)xp)[i] : make_float4(0.f, 0.f, 0.f, 0.f);
        f16x8 lo, hi;
        CVT16(lo, hi);
        xs8[(0 * 4 + skh * 2 + 0) * 128 + srow] = lo;
        xs8[(0 * 4 + skh * 2 + 1) * 128 + srow] = hi;
    }
    __syncthreads();

    f32x4 acc[2][8];
#pragma unroll
    for (int mf = 0; mf < 2; ++mf)
#pragma unroll
        for (int nf = 0; nf < 8; ++nf) acc[mf][nf] = (f32x4){0.f, 0.f, 0.f, 0.f};

    const int kgl = lane >> 4;
    const int l15 = lane & 15;
    const int mb  = (wv << 5) + l15;

#pragma unroll
    for (int H = 0; H < 2; ++H) {
        // stage W half H: k = H*128 + kl, frag layout [kl>>3][n] sub (kl&7)
        if (a256) {
#pragma unroll
            for (int itr = 0; itr < 8; ++itr) {
                const int e  = itr * 2048 + t * 8;
                const int kl = e >> 7;
                const int n0 = e & 127;
                const float4 a4 = *(const float4*)(w + (size_t)((H << 7) + kl) * 128 + n0);
                const float4 b4 = *(const float4*)(w + (size_t)((H << 7) + kl) * 128 + n0 + 4);
                __half* d = (__half*)wt8h + (size_t)(((kl >> 3) << 7) + n0) * 8 + (kl & 7);
                d[0]  = __float2half(a4.x);
                d[8]  = __float2half(a4.y);
                d[16] = __float2half(a4.z);
                d[24] = __float2half(a4.w);
                d[32] = __float2half(b4.x);
                d[40] = __float2half(b4.y);
                d[48] = __float2half(b4.z);
                d[56] = __float2half(b4.w);
            }
        }
        __syncthreads();

#pragma unroll
        for (int ksl = 0; ksl < 4; ++ksl) {
            const int ks  = H * 4 + ksl;
            const int cur = ks & 1;
            if (a256 && ks < 7) {
#pragma unroll
                for (int i = 0; i < 4; ++i)
                    xr[i] = rv ? ((const float4*)(xp + (ks + 1) * 32))[i]
                               : make_float4(0.f, 0.f, 0.f, 0.f);
            }
            if (a256) {
                const f16x8 b0 = xs8[(cur * 4 + kgl) * 128 + mb];
                const f16x8 b1 = xs8[(cur * 4 + kgl) * 128 + mb + 16];
                const int abase = ((ksl * 4 + kgl) << 7) + l15;
#pragma unroll
                for (int nf = 0; nf < 8; ++nf) {
                    const f16x8 a = wt8h[abase + (nf << 4)];
                    acc[0][nf] = __builtin_amdgcn_mfma_f32_16x16x32_f16(a, b0, acc[0][nf], 0, 0, 0);
                    acc[1][nf] = __builtin_amdgcn_mfma_f32_16x16x32_f16(a, b1, acc[1][nf], 0, 0, 0);
                }
            }
            if (a256 && ks < 7) {
                f16x8 lo, hi;
                CVT16(lo, hi);
                xs8[((cur ^ 1) * 4 + skh * 2 + 0) * 128 + srow] = lo;
                xs8[((cur ^ 1) * 4 + skh * 2 + 1) * 128 + srow] = hi;
            }
            __syncthreads();
        }
    }

    if (a256) {
        const int rg = lane >> 4;
#pragma unroll
        for (int mf = 0; mf < 2; ++mf) {
            const int m = row0 + (wv << 5) + (mf << 4) + l15;
            if (m < N_NODES) {
                __half* hp = h + (size_t)m * OUT_DIM + (rg << 2);
#pragma unroll
                for (int nf = 0; nf < 8; ++nf) {
                    union { ushort4 u; __half f[4]; } o;
                    o.f[0] = __float2half(acc[mf][nf][0]);
                    o.f[1] = __float2half(acc[mf][nf][1]);
                    o.f[2] = __float2half(acc[mf][nf][2]);
                    o.f[3] = __float2half(acc[mf][nf][3]);
                    *(ushort4*)(hp + (nf << 4)) = o.u;
                }
            }
        }
    }
}

// ---------------------------------------------------------------------------
// Dispatch 2: fine scatter. Block (sb, p) reads its 32 dense source runs
// (starts from cstartarr, L2-hot), LDS counting sort by fine bin (36 KB),
// dense write to ebuf[(sb*8+p)*ECAP ...] + per-(bin,p) start/count tables.
// Overflow (lsort > ECAP or per-(bin,p) run > SEGP, both ~+8..11 sigma)
// -> full-row ovfbuf replayed by the gather.
// ---------------------------------------------------------------------------
__global__ __launch_bounds__(512) void scatter_fine(const int* __restrict__ cstartarr,
                                                    int* __restrict__ fs,
                                                    int* __restrict__ fc,
                                                    int* __restrict__ ovfcnt,
                                                    const int2* __restrict__ cbuf,
                                                    int2* __restrict__ ebuf,
                                                    int2* __restrict__ ovfbuf) {
    __shared__ int2 lsort[ECAP];           // 36 KB
    __shared__ int  hist[32], cstart[32], fcv[32];
    __shared__ int  scnt[32], sstart[32];
    __shared__ int  stot;

    const int t    = threadIdx.x;
    const int lane = t & 63;
    const int wv   = t >> 6;
    const int sb   = blockIdx.x / NPART;
    const int p    = blockIdx.x % NPART;

    if (t < 32) {
        const int blk = p * 32 + t;
        const int s0 = cstartarr[blk * 50 + sb];
        const int s1 = cstartarr[blk * 50 + sb + 1];
        scnt[t]   = s1 - s0;
        sstart[t] = blk * EPB_S + s0;
        hist[t]   = 0;
    }
    __syncthreads();

    // pass 1: histogram by fine bin (wave owns 4 source runs)
    for (int j = 0; j < 4; ++j) {
        const int s = (wv << 2) + j;
        const int c = scnt[s];
        const int base = sstart[s];
        for (int i = lane; i < c; i += 64)
            atomicAdd(&hist[(cbuf[base + i].x >> 21) & 31], 1);
    }
    __syncthreads();

    if (t < 32) {                          // scan 32 fine bins
        const int v = hist[t];
        int s = v;
#pragma unroll
        for (int off = 1; off < 32; off <<= 1) {
            const int u = __shfl_up(s, off);
            if (t >= off) s += u;
        }
        if (t == 31) stot = s;
        cstart[t] = s - v;
        hist[t]   = s - v;                 // cursor
    }
    __syncthreads();

    // pass 2: place into LDS sorted by fine bin (cbuf re-read, L2-hot)
    for (int j = 0; j < 4; ++j) {
        const int s = (wv << 2) + j;
        const int c = scnt[s];
        const int base = sstart[s];
        for (int i = lane; i < c; i += 64) {
            const int2 rc = cbuf[base + i];
            const int fb = (rc.x >> 21) & 31;
            const int pos = atomicAdd(&hist[fb], 1);
            const int lrow = (rc.x >> 16) & 31;
            if (pos < ECAP) {
                lsort[pos] = make_int2((rc.x & 0xFFFF) | (lrow << 16) | (fb << 21), rc.y);
            } else {
                const int q = atomicAdd(ovfcnt, 1);      // statistically unreachable
                if (q < OVF_CAP) ovfbuf[q] = rc;         // full-row format
            }
        }
    }
    __syncthreads();

    if (t < 32) {                          // per-bin visible count (clamped)
        int c = hist[t] - cstart[t];
        if (c > SEGP) c = SEGP;
        if (cstart[t] + c > ECAP) c = (cstart[t] < ECAP) ? (ECAP - cstart[t]) : 0;
        fcv[t] = c;
        fs[(sb * 32 + t) * NPART + p] = cstart[t];
        fc[(sb * 32 + t) * NPART + p] = c;
    }
    __syncthreads();

    // pass 3: dense coalesced write-out; spill the clamped tail
    const int tot = min(stot, ECAP);
    int2* dst = ebuf + (size_t)(sb * NPART + p) * ECAP;
    for (int i = t; i < tot; i += 512) {
        const int2 rc = lsort[i];
        dst[i] = rc;
        const int fb  = (rc.x >> 21) & 31;
        const int off = i - cstart[fb];
        if (off >= fcv[fb]) {                            // statistically unreachable
            const int q = atomicAdd(ovfcnt, 1);
            if (q < OVF_CAP) {
                const int row = (sb << SB_SH) | (fb << BIN_SH) | ((rc.x >> 16) & 31);
                ovfbuf[q] = make_int2((int)(((unsigned)row << 16) | (unsigned)(rc.x & 0xFFFF)), rc.y);
            }
        }
    }
}

// ---------------------------------------------------------------------------
// Dispatch 3: FUSED sort+gather (round-9 core, addressing adapted to the
// dense ebuf slabs). One block per 32-row bin; stage the bin's 8 part-runs
// to urec (single ebuf read), 256-class (row,octant) counting sort, then
// per-wave 4-row register gather with fused leaky-ReLU.
// ---------------------------------------------------------------------------
#define NCLS 256

#define STAGE(IT, HV, VV) do {                                                  \
    _Pragma("unroll")                                                           \
    for (int q = 0; q < 4; ++q) {                                               \
        const int idx = beg[q] + ((IT) << 2) + grp;                             \
        const bool vld = idx < end[q];                                          \
        const int2 r = srec[vld ? idx : last];                                  \
        VV[q] = vld ? __int_as_float(r.y) : 0.f;                                \
        HV[q] = *(const f16x8*)(h + (size_t)(r.x & 0xFFFF) * OUT_DIM + (gl << 3)); \
    }                                                                           \
} while (0)

__global__ __launch_bounds__(512, 4) void sort_gather(const int* __restrict__ fs,
                                                      const int* __restrict__ fc,
                                                      const int* __restrict__ ovfcnt,
                                                      const int2* __restrict__ ebuf,
                                                      const int2* __restrict__ ovfbuf,
                                                      const __half* __restrict__ h,
                                                      float* __restrict__ out) {
    __shared__ int2 urec[CAPG];            // 16 KB raw staged records
    __shared__ int2 srec[CAPG];            // 16 KB sorted records
    __shared__ int  hist[NCLS];
    __shared__ int  pfx[NCLS];
    __shared__ int  rowoff_l[BIN_ROWS + 1];
    __shared__ int  wsum[4];
    __shared__ int  poff[NPART + 1];
    __shared__ int  fsrt[NPART];

    const int t    = threadIdx.x;
    const int bin  = blockIdx.x;
    const int wv   = t >> 6;
    const int lane = t & 63;
    const int sb   = bin >> 5;

    if (t < NCLS) hist[t] = 0;
    if (t < NPART) fsrt[t] = fs[bin * NPART + t];
    if (t == 0) {
        int a = 0;
        poff[0] = 0;
#pragma unroll
        for (int p = 0; p < NPART; ++p) { a += fc[bin * NPART + p]; poff[p + 1] = a; }
    }
    __syncthreads();
    const int cnt = poff[NPART];

    // ---- pass 1: stage part wv to urec (single ebuf read) + histogram ----
    {
        const int cp = poff[wv + 1] - poff[wv];
        const int2* src = ebuf + (size_t)(sb * NPART + wv) * ECAP + fsrt[wv];
        const int ub = poff[wv];
        for (int i = lane; i < cp; i += 64) {
            const int2 r = src[i];
            urec[ub + i] = r;
            atomicAdd(&hist[(((r.x >> 16) & 31) << 3) | ((r.x & 0xFFFF) >> 13)], 1);
        }
    }
    __syncthreads();

    // ---- 256-class scan: 4-wave shfl scan + tiny combine ----
    {
        const int v = (t < NCLS) ? hist[t] : 0;
        int s = v;
#pragma unroll
        for (int off = 1; off < 64; off <<= 1) {
            const int u = __shfl_up(s, off);
            if (lane >= off) s += u;
        }
        if (t < NCLS && lane == 63) wsum[wv] = s;
        __syncthreads();
        if (t == 0) {
            int a = 0;
#pragma unroll
            for (int i = 0; i < 4; ++i) { const int c = wsum[i]; wsum[i] = a; a += c; }
        }
        __syncthreads();
        if (t < NCLS) {
            const int incl = s + wsum[wv];
            pfx[t]  = incl;
            hist[t] = incl - v;
        }
    }
    __syncthreads();
    if (t < BIN_ROWS) rowoff_l[t] = t ? pfx[(t << 3) - 1] : 0;
    if (t == BIN_ROWS) rowoff_l[BIN_ROWS] = cnt;
    __syncthreads();

    // ---- pass 2: counting sort LDS -> LDS ----
    for (int i = t; i < cnt; i += 512) {
        const int2 r = urec[i];
        const int cls = (((r.x >> 16) & 31) << 3) | ((r.x & 0xFFFF) >> 13);
        const int pos = atomicAdd(&hist[cls], 1);
        srec[pos] = r;
    }
    __syncthreads();

    // ---- gather: wave owns 4 rows ----
    const int grp = lane >> 4;
    const int gl  = lane & 15;
    const int r0  = wv << 2;
    const int last = cnt > 0 ? cnt - 1 : 0;

    int beg[4], end[4];
#pragma unroll
    for (int q = 0; q < 4; ++q) { beg[q] = rowoff_l[r0 + q]; end[q] = rowoff_l[r0 + q + 1]; }
    int nmax = 0;
#pragma unroll
    for (int q = 0; q < 4; ++q) nmax = max(nmax, end[q] - beg[q]);
    const int iters = (nmax + 3) >> 2;

    f32x8 acc[4];
#pragma unroll
    for (int q = 0; q < 4; ++q) acc[q] = (f32x8){0.f,0.f,0.f,0.f,0.f,0.f,0.f,0.f};

    if (cnt > 0 && iters > 0) {
        f16x8 hc[4], hn[4];
        float vc[4], vn[4];
        STAGE(0, hc, vc);
        for (int it = 0; it < iters; ++it) {
            const int itn = (it + 1 < iters) ? it + 1 : it;
            STAGE(itn, hn, vn);
            __builtin_amdgcn_sched_barrier(0);
#pragma unroll
            for (int q = 0; q < 4; ++q)
#pragma unroll
                for (int j = 0; j < 8; ++j) acc[q][j] += vc[q] * (float)hc[q][j];
            __builtin_amdgcn_sched_barrier(0);
#pragma unroll
            for (int q = 0; q < 4; ++q) { hc[q] = hn[q]; vc[q] = vn[q]; }
        }
    }

    // ---- overflow replay (0 in practice) ----
    int novf = *ovfcnt;
    if (novf > OVF_CAP) novf = OVF_CAP;
    for (int e = 0; e < novf; ++e) {
        const int2 rec = ovfbuf[e];
        const unsigned urow = ((unsigned)rec.x) >> 16;
        if ((int)(urow >> BIN_SH) == bin && grp == 0) {
            const int lr = (int)(urow & (BIN_ROWS - 1)) - r0;
            if (lr >= 0 && lr < 4) {
                const float v = __int_as_float(rec.y);
                const f16x8 hv = *(const f16x8*)(h + (size_t)(rec.x & 0xFFFF) * OUT_DIM + (gl << 3));
#pragma unroll
                for (int q = 0; q < 4; ++q)
                    if (q == lr)
#pragma unroll
                        for (int j = 0; j < 8; ++j) acc[q][j] += v * (float)hv[j];
            }
        }
    }

    // ---- reduce across the 4 edge-slot groups ----
#pragma unroll
    for (int q = 0; q < 4; ++q)
#pragma unroll
        for (int j = 0; j < 8; ++j) {
            float x = acc[q][j];
            x += __shfl_xor(x, 16);
            x += __shfl_xor(x, 32);
            acc[q][j] = x;
        }

    float res[8];
#pragma unroll
    for (int j = 0; j < 8; ++j) {
        float x = acc[0][j];
        x = (grp == 1) ? acc[1][j] : x;
        x = (grp == 2) ? acc[2][j] : x;
        x = (grp == 3) ? acc[3][j] : x;
        res[j] = lrelu(x);
    }
    const int grow = (bin << BIN_SH) + r0 + grp;
    if (grow < N_NODES) {
        float* op = out + (size_t)grow * OUT_DIM + (gl << 3);
        *(float4*)op       = make_float4(res[0], res[1], res[2], res[3]);
        *(float4*)(op + 4) = make_float4(res[4], res[5], res[6], res[7]);
    }
}

// ---------------------------------------------------------------------------
// Launch: 3 dispatches, no memset. prep (coarse || gemm || zero) ->
// scatter_fine -> sort_gather. Workspace ~41 MB, no aliasing (gemm and
// coarse are concurrent now).
// ---------------------------------------------------------------------------
extern "C" void kernel_launch(void* const* d_in, const int* in_sizes, int n_in,
                              void* d_out, int out_size, void* d_ws, size_t ws_size,
                              hipStream_t stream) {
    const float* x    = (const float*)d_in[0];
    const float* w    = (const float*)d_in[1];
    const float* vals = (const float*)d_in[2];
    const int*   rows = (const int*)d_in[3];
    const int*   cols = (const int*)d_in[4];
    float* out = (float*)d_out;

    char* ws = (char*)d_ws;
    size_t off = 0;
    auto alloc = [&](size_t bytes) {
        void* p = ws + off;
        off = (off + bytes + 255) & ~(size_t)255;
        return p;
    };
    int2*   cbuf     = (int2*)  alloc((size_t)N_EDGES * sizeof(int2));               // 12.8 MB dense
    __half* h        = (__half*)alloc((size_t)N_NODES * OUT_DIM * sizeof(__half));   // 12.8 MB
    int2*   ebuf     = (int2*)  alloc((size_t)NSB * NPART * ECAP * sizeof(int2));    // 14.5 MB
    int2*   ovfbuf   = (int2*)  alloc((size_t)OVF_CAP * sizeof(int2));               // 0.5 MB
    int*    cstartarr= (int*)   alloc((size_t)SCAT_BLOCKS * 50 * sizeof(int));       // 50 KB
    int*    fs       = (int*)   alloc((size_t)NBIN_PAD * NPART * sizeof(int));       // 50 KB
    int*    fc       = (int*)   alloc((size_t)NBIN_PAD * NPART * sizeof(int));       // 50 KB
    int*    ovfcnt   = (int*)   alloc(sizeof(int));

    prep<<<PREP_BLOCKS, 512, 0, stream>>>(rows, cols, vals, x, w,
                                          cstartarr, ovfcnt, cbuf, h);
    scatter_fine<<<NSB * NPART, 512, 0, stream>>>(cstartarr, fs, fc, ovfcnt,
                                                  cbuf, ebuf, ovfbuf);
    sort_gather<<<NBIN_PAD, 512, 0, stream>>>(fs, fc, ovfcnt, ebuf, ovfbuf, h, out);
}

// Round 11
// 192.540 us; speedup vs baseline: 1.0637x; 1.0529x over previous
//
#include <hip/hip_runtime.h>
#include <hip/hip_fp16.h>

#define N_NODES 50000
#define N_EDGES 1600000
#define IN_DIM 256
#define OUT_DIM 128
#define NEG_SLOPE 0.01f

// ---- geometry ----
#define SB_SH     10
#define NSB       49                       // super-bins of 1024 rows
#define BIN_SH    4
#define BIN_ROWS  16                       // 16-row fine bins (was 32)
#define NBIN_PAD  (NSB * 64)               // 3136 bins (50000/16 = 3125 real)
#define NPART     16                       // fine parts per super-bin (was 8)
#define ECAP      2560                     // records per (sb,part) slab (+11 sigma)
#define SEGP      96                       // per-(bin,part) clamp (+11 sigma)
#define CAPG      (NPART * SEGP)           // 1536 gather LDS records (12 KB)
#define OVF_CAP   65536

#define SCAT_BLOCKS 256
#define EPB_S (N_EDGES / SCAT_BLOCKS)      // 6250
#define SCAT_ITERS ((EPB_S + 511) / 512)   // 13

#define BM 128
#define GEMM_BLOCKS ((N_NODES + BM - 1) / BM)  // 391
#define PREP_BLOCKS (SCAT_BLOCKS + GEMM_BLOCKS + 1)

typedef _Float16 f16x8 __attribute__((ext_vector_type(8)));
typedef float    f32x4 __attribute__((ext_vector_type(4)));
typedef float    f32x8 __attribute__((ext_vector_type(8)));

__device__ __forceinline__ float lrelu(float v) {
    return v >= 0.f ? v : NEG_SLOPE * v;
}

#define CVT16(lo, hi) do { \
    lo[0]=(_Float16)xr[0].x; lo[1]=(_Float16)xr[0].y; lo[2]=(_Float16)xr[0].z; lo[3]=(_Float16)xr[0].w; \
    lo[4]=(_Float16)xr[1].x; lo[5]=(_Float16)xr[1].y; lo[6]=(_Float16)xr[1].z; lo[7]=(_Float16)xr[1].w; \
    hi[0]=(_Float16)xr[2].x; hi[1]=(_Float16)xr[2].y; hi[2]=(_Float16)xr[2].z; hi[3]=(_Float16)xr[2].w; \
    hi[4]=(_Float16)xr[3].x; hi[5]=(_Float16)xr[3].y; hi[6]=(_Float16)xr[3].z; hi[7]=(_Float16)xr[3].w; \
} while (0)

// ---------------------------------------------------------------------------
// Dispatch 1 "prep": UNCHANGED from round 10 (isolating this round's
// variables to fine + gather).
//   blocks 0..255   : coarse scatter (LDS sort by super-bin, dense write)
//   blocks 256..646 : gemm h = x@W (self-staged W, MFMA)
//   block  647      : zero ovfcnt
// ---------------------------------------------------------------------------
__global__ __launch_bounds__(512, 2) void prep(const int* __restrict__ rows,
                                               const int* __restrict__ cols,
                                               const float* __restrict__ vals,
                                               const float* __restrict__ x,
                                               const float* __restrict__ w,
                                               int* __restrict__ cstartarr,
                                               int* __restrict__ ovfcnt,
                                               int2* __restrict__ cbuf,
                                               __half* __restrict__ h) {
    __shared__ __attribute__((aligned(16))) char smem[50432];
    const int bid = blockIdx.x;
    const int t   = threadIdx.x;

    if (bid >= SCAT_BLOCKS + GEMM_BLOCKS) {        // zero-block
        if (t == 0) *ovfcnt = 0;
        return;
    }

    if (bid < SCAT_BLOCKS) {
        // ================= coarse scatter role =================
        int2* lsort  = (int2*)smem;                // 6250 rec = 50,000 B
        int*  hist   = (int*)(smem + 50000);       // 49
        int*  cstart = (int*)(smem + 50200);       // 49
        const int lane  = t & 63;
        const int blk   = bid;
        const int ebase = blk * EPB_S;

        if (t < NSB) hist[t] = 0;
        __syncthreads();

        int myr[SCAT_ITERS];
#pragma unroll
        for (int k = 0; k < SCAT_ITERS; ++k) {
            const int i = k * 512 + t;
            myr[k] = -1;
            if (i < EPB_S) {
                myr[k] = rows[ebase + i];
                atomicAdd(&hist[myr[k] >> SB_SH], 1);
            }
        }
        __syncthreads();

        if (t < 64) {                              // scan 49 sbins (wave 0)
            const int v = (t < NSB) ? hist[t] : 0;
            int s = v;
#pragma unroll
            for (int off = 1; off < 64; off <<= 1) {
                const int u = __shfl_up(s, off);
                if (lane >= off) s += u;
            }
            if (t < NSB) { cstart[t] = s - v; hist[t] = s - v; }
        }
        __syncthreads();

#pragma unroll
        for (int k = 0; k < SCAT_ITERS; ++k) {
            const int i = k * 512 + t;
            if (i < EPB_S) {
                const int e = ebase + i;
                const int r = myr[k];
                const int pos = atomicAdd(&hist[r >> SB_SH], 1);
                lsort[pos] = make_int2((int)(((unsigned)r << 16) | (unsigned)cols[e]),
                                       __float_as_int(vals[e]));
            }
        }
        __syncthreads();

        {
            const int4* src = (const int4*)lsort;
            int4* dst = (int4*)(cbuf + (size_t)blk * EPB_S);
            for (int i = t; i < EPB_S / 2; i += 512) dst[i] = src[i];
        }
        if (t < NSB)  cstartarr[blk * 50 + t]   = cstart[t];
        if (t == NSB) cstartarr[blk * 50 + NSB] = EPB_S;
        return;
    }

    // ================= gemm role (t<256 active) =================
    f16x8* wt8h = (f16x8*)smem;                    // 32 KB half-W frag
    f16x8* xs8  = (f16x8*)(smem + 32768);          // 16 KB x double-buffer
    const int a256 = (t < 256);
    const int lane = t & 63;
    const int wv   = t >> 6;
    const int row0 = (bid - SCAT_BLOCKS) * BM;

    const int srow = t >> 1;
    const int skh  = t & 1;
    const int grow = row0 + srow;
    const bool rv  = a256 && (grow < N_NODES);
    const float* xp = x + (size_t)(rv ? grow : 0) * IN_DIM + skh * 16;

    float4 xr[4];
    if (a256) {
#pragma unroll
        for (int i = 0; i < 4; ++i)
            xr[i] = rv ? ((const float4*)xp)[i] : make_float4(0.f, 0.f, 0.f, 0.f);
        f16x8 lo, hi;
        CVT16(lo, hi);
        xs8[(0 * 4 + skh * 2 + 0) * 128 + srow] = lo;
        xs8[(0 * 4 + skh * 2 + 1) * 128 + srow] = hi;
    }
    __syncthreads();

    f32x4 acc[2][8];
#pragma unroll
    for (int mf = 0; mf < 2; ++mf)
#pragma unroll
        for (int nf = 0; nf < 8; ++nf) acc[mf][nf] = (f32x4){0.f, 0.f, 0.f, 0.f};

    const int kgl = lane >> 4;
    const int l15 = lane & 15;
    const int mb  = (wv << 5) + l15;

#pragma unroll
    for (int H = 0; H < 2; ++H) {
        if (a256) {
#pragma unroll
            for (int itr = 0; itr < 8; ++itr) {
                const int e  = itr * 2048 + t * 8;
                const int kl = e >> 7;
                const int n0 = e & 127;
                const float4 a4 = *(const float4*)(w + (size_t)((H << 7) + kl) * 128 + n0);
                const float4 b4 = *(const float4*)(w + (size_t)((H << 7) + kl) * 128 + n0 + 4);
                __half* d = (__half*)wt8h + (size_t)(((kl >> 3) << 7) + n0) * 8 + (kl & 7);
                d[0]  = __float2half(a4.x);
                d[8]  = __float2half(a4.y);
                d[16] = __float2half(a4.z);
                d[24] = __float2half(a4.w);
                d[32] = __float2half(b4.x);
                d[40] = __float2half(b4.y);
                d[48] = __float2half(b4.z);
                d[56] = __float2half(b4.w);
            }
        }
        __syncthreads();

#pragma unroll
        for (int ksl = 0; ksl < 4; ++ksl) {
            const int ks  = H * 4 + ksl;
            const int cur = ks & 1;
            if (a256 && ks < 7) {
#pragma unroll
                for (int i = 0; i < 4; ++i)
                    xr[i] = rv ? ((const float4*)(xp + (ks + 1) * 32))[i]
                               : make_float4(0.f, 0.f, 0.f, 0.f);
            }
            if (a256) {
                const f16x8 b0 = xs8[(cur * 4 + kgl) * 128 + mb];
                const f16x8 b1 = xs8[(cur * 4 + kgl) * 128 + mb + 16];
                const int abase = ((ksl * 4 + kgl) << 7) + l15;
#pragma unroll
                for (int nf = 0; nf < 8; ++nf) {
                    const f16x8 a = wt8h[abase + (nf << 4)];
                    acc[0][nf] = __builtin_amdgcn_mfma_f32_16x16x32_f16(a, b0, acc[0][nf], 0, 0, 0);
                    acc[1][nf] = __builtin_amdgcn_mfma_f32_16x16x32_f16(a, b1, acc[1][nf], 0, 0, 0);
                }
            }
            if (a256 && ks < 7) {
                f16x8 lo, hi;
                CVT16(lo, hi);
                xs8[((cur ^ 1) * 4 + skh * 2 + 0) * 128 + srow] = lo;
                xs8[((cur ^ 1) * 4 + skh * 2 + 1) * 128 + srow] = hi;
            }
            __syncthreads();
        }
    }

    if (a256) {
        const int rg = lane >> 4;
#pragma unroll
        for (int mf = 0; mf < 2; ++mf) {
            const int m = row0 + (wv << 5) + (mf << 4) + l15;
            if (m < N_NODES) {
                __half* hp = h + (size_t)m * OUT_DIM + (rg << 2);
#pragma unroll
                for (int nf = 0; nf < 8; ++nf) {
                    union { ushort4 u; __half f[4]; } o;
                    o.f[0] = __float2half(acc[mf][nf][0]);
                    o.f[1] = __float2half(acc[mf][nf][1]);
                    o.f[2] = __float2half(acc[mf][nf][2]);
                    o.f[3] = __float2half(acc[mf][nf][3]);
                    *(ushort4*)(hp + (nf << 4)) = o.u;
                }
            }
        }
    }
}

// ---------------------------------------------------------------------------
// Dispatch 2: fine scatter, NPART=16 -> 784 blocks (was 392 at 1.5/CU,
// grid-starved). Block (sb,p) reads 16 dense source runs (L2-hot), LDS
// counting sort by the 64 fine bins (fb = key bits 20..25, positional --
// no repack; records stay { row<<16|col, val } end-to-end), dense coalesced
// slab write + per-(bin,part) start/count tables. 21 KB LDS, 512 thr.
// ---------------------------------------------------------------------------
__global__ __launch_bounds__(512) void scatter_fine(const int* __restrict__ cstartarr,
                                                    int* __restrict__ fs,
                                                    int* __restrict__ fc,
                                                    int* __restrict__ ovfcnt,
                                                    const int2* __restrict__ cbuf,
                                                    int2* __restrict__ ebuf,
                                                    int2* __restrict__ ovfbuf) {
    __shared__ int2 lsort[ECAP];           // 20.5 KB
    __shared__ int  hist[64], cstart[64], fcv[64];
    __shared__ int  scnt[16], sstart[16];
    __shared__ int  stot;

    const int t    = threadIdx.x;
    const int lane = t & 63;
    const int wv   = t >> 6;               // 0..7, owns 2 source runs
    const int sb   = blockIdx.x / NPART;
    const int p    = blockIdx.x % NPART;

    if (t < 16) {
        const int blk = p * 16 + t;
        const int s0 = cstartarr[blk * 50 + sb];
        const int s1 = cstartarr[blk * 50 + sb + 1];
        scnt[t]   = s1 - s0;
        sstart[t] = blk * EPB_S + s0;
    }
    if (t < 64) hist[t] = 0;
    __syncthreads();

    // pass 1: histogram by fine bin
    for (int j = 0; j < 2; ++j) {
        const int s = (wv << 1) | j;
        const int c = scnt[s];
        const int base = sstart[s];
        for (int i = lane; i < c; i += 64)
            atomicAdd(&hist[((unsigned)cbuf[base + i].x >> 20) & 63], 1);
    }
    __syncthreads();

    if (t < 64) {                          // scan 64 fine bins (wave 0)
        const int v = hist[t];
        int s = v;
#pragma unroll
        for (int off = 1; off < 64; off <<= 1) {
            const int u = __shfl_up(s, off);
            if (t >= off) s += u;
        }
        if (t == 63) stot = s;
        cstart[t] = s - v;
        hist[t]   = s - v;                 // cursor
    }
    __syncthreads();

    // pass 2: place into LDS sorted by fine bin (cbuf re-read, L2-hot)
    for (int j = 0; j < 2; ++j) {
        const int s = (wv << 1) | j;
        const int c = scnt[s];
        const int base = sstart[s];
        for (int i = lane; i < c; i += 64) {
            const int2 rc = cbuf[base + i];
            const int fb = ((unsigned)rc.x >> 20) & 63;
            const int pos = atomicAdd(&hist[fb], 1);
            if (pos < ECAP) {
                lsort[pos] = rc;
            } else {
                const int q = atomicAdd(ovfcnt, 1);      // statistically unreachable
                if (q < OVF_CAP) ovfbuf[q] = rc;
            }
        }
    }
    __syncthreads();

    if (t < 64) {                          // per-bin visible count (clamped)
        int c = hist[t] - cstart[t];
        if (c > SEGP) c = SEGP;
        if (cstart[t] + c > ECAP) c = (cstart[t] < ECAP) ? (ECAP - cstart[t]) : 0;
        fcv[t] = c;
        fs[(sb * 64 + t) * NPART + p] = cstart[t];
        fc[(sb * 64 + t) * NPART + p] = c;
    }
    __syncthreads();

    // pass 3: dense coalesced write-out; spill clamped tail
    const int tot = min(stot, ECAP);
    int2* dst = ebuf + (size_t)(sb * NPART + p) * ECAP;
    for (int i = t; i < tot; i += 512) {
        const int2 rc = lsort[i];
        dst[i] = rc;
        const int fb  = ((unsigned)rc.x >> 20) & 63;
        const int off = i - cstart[fb];
        if (off >= fcv[fb]) {                            // statistically unreachable
            const int q = atomicAdd(ovfcnt, 1);
            if (q < OVF_CAP) ovfbuf[q] = rc;
        }
    }
}

// ---------------------------------------------------------------------------
// Dispatch 3: FUSED sort+gather, RESIDENCY-FIRST redesign. Evidence: gather
// rate tracks occupancy (r2: 52% occ -> 55 us; r7-10: 33% -> 63.5 us), same
// FETCH. So: 16-row bins -> 3136 blocks of 256 THREADS (12.2/CU, wave-capped
// 8 blocks/CU = 100% theoretical), srec-only LDS (12 KB; hist pass re-reads
// the L2-hot ebuf slabs instead of a urec stage). Per-wave 2-row-pair loop
// is round 2's proven 28-VGPR shape.
// Sort class = lrow<<4 | col>>12 (1 MB h slices, phase-local L2).
// ---------------------------------------------------------------------------
#define NCLS 256

__global__ __launch_bounds__(256) void sort_gather(const int* __restrict__ fs,
                                                   const int* __restrict__ fc,
                                                   const int* __restrict__ ovfcnt,
                                                   const int2* __restrict__ ebuf,
                                                   const int2* __restrict__ ovfbuf,
                                                   const __half* __restrict__ h,
                                                   float* __restrict__ out) {
    __shared__ int2 srec[CAPG];            // 12 KB sorted records
    __shared__ int  hist[NCLS];
    __shared__ int  pfx[NCLS];
    __shared__ int  rowoff_l[BIN_ROWS + 1];
    __shared__ int  wsum[4];
    __shared__ int  poff[NPART + 1];
    __shared__ int  fsrt[NPART];

    const int t    = threadIdx.x;          // 0..255
    const int bin  = blockIdx.x;
    const int wv   = t >> 6;               // 0..3
    const int lane = t & 63;
    const int sb   = bin >> 6;

    hist[t] = 0;
    if (t < NPART) fsrt[t] = fs[bin * NPART + t];
    if (t == 0) {
        int a = 0;
        poff[0] = 0;
#pragma unroll
        for (int p = 0; p < NPART; ++p) { a += fc[bin * NPART + p]; poff[p + 1] = a; }
    }
    __syncthreads();
    const int cnt = poff[NPART];

    // ---- pass 1: per-(lrow, col-slice) histogram (wave stages 4 parts) ----
#pragma unroll
    for (int j = 0; j < 4; ++j) {
        const int p  = (wv << 2) + j;
        const int cp = poff[p + 1] - poff[p];
        const int2* src = ebuf + (size_t)(sb * NPART + p) * ECAP + fsrt[p];
        for (int i = lane; i < cp; i += 64) {
            const int k = src[i].x;
            atomicAdd(&hist[(((k >> 16) & 15) << 4) | ((k & 0xFFFF) >> 12)], 1);
        }
    }
    __syncthreads();

    // ---- 256-class scan: 4-wave shfl scan + combine ----
    {
        const int v = hist[t];
        int s = v;
#pragma unroll
        for (int off = 1; off < 64; off <<= 1) {
            const int u = __shfl_up(s, off);
            if (lane >= off) s += u;
        }
        if (lane == 63) wsum[wv] = s;
        __syncthreads();
        if (t == 0) {
            int a = 0;
#pragma unroll
            for (int i = 0; i < 4; ++i) { const int c = wsum[i]; wsum[i] = a; a += c; }
        }
        __syncthreads();
        const int incl = s + wsum[wv];
        pfx[t]  = incl;
        hist[t] = incl - v;                // exclusive -> sort cursor
    }
    __syncthreads();
    if (t < BIN_ROWS) rowoff_l[t] = t ? pfx[(t << 4) - 1] : 0;
    if (t == BIN_ROWS) rowoff_l[BIN_ROWS] = cnt;
    __syncthreads();

    // ---- pass 2: counting sort into srec (ebuf re-read, L2-hot) ----
#pragma unroll
    for (int j = 0; j < 4; ++j) {
        const int p  = (wv << 2) + j;
        const int cp = poff[p + 1] - poff[p];
        const int2* src = ebuf + (size_t)(sb * NPART + p) * ECAP + fsrt[p];
        for (int i = lane; i < cp; i += 64) {
            const int2 r = src[i];
            const int cls = (((r.x >> 16) & 15) << 4) | ((r.x & 0xFFFF) >> 12);
            const int pos = atomicAdd(&hist[cls], 1);
            srec[pos] = r;
        }
    }
    __syncthreads();

    // ---- gather: wave owns 4 rows in 2 pairs (round-2 proven shape) ----
    const int grp = lane >> 4;
    const int gl  = lane & 15;
    int novf = *ovfcnt;
    if (novf > OVF_CAP) novf = OVF_CAP;

    for (int pp = 0; pp < 2; ++pp) {
        const int lr0 = (wv << 2) + 2 * pp;
        const int lr1 = lr0 + 1;
        const int b0 = rowoff_l[lr0], e0 = rowoff_l[lr0 + 1];
        const int b1 = rowoff_l[lr1], e1 = rowoff_l[lr1 + 1];
        const int n0 = e0 - b0, n1 = e1 - b1;
        const int nmax = n0 > n1 ? n0 : n1;
        const int iters = (nmax + 3) >> 2;

        f32x8 a0 = (f32x8){0.f,0.f,0.f,0.f,0.f,0.f,0.f,0.f};
        f32x8 a1 = (f32x8){0.f,0.f,0.f,0.f,0.f,0.f,0.f,0.f};

        for (int it = 0; it < iters; ++it) {
            const int i0 = b0 + (it << 2) + grp;
            const int i1 = b1 + (it << 2) + grp;
            const bool v0i = i0 < e0;
            const bool v1i = i1 < e1;
            const int2 rA = srec[v0i ? i0 : 0];
            const int2 rB = srec[v1i ? i1 : 0];
            const float vA = v0i ? __int_as_float(rA.y) : 0.f;
            const float vB = v1i ? __int_as_float(rB.y) : 0.f;
            const f16x8 hA = *(const f16x8*)(h + (size_t)(rA.x & 0xFFFF) * OUT_DIM + (gl << 3));
            const f16x8 hB = *(const f16x8*)(h + (size_t)(rB.x & 0xFFFF) * OUT_DIM + (gl << 3));
#pragma unroll
            for (int j = 0; j < 8; ++j) {
                a0[j] += vA * (float)hA[j];
                a1[j] += vB * (float)hB[j];
            }
        }

        // ---- overflow replay (0 in practice) ----
        for (int e = 0; e < novf; ++e) {
            const int2 rec = ovfbuf[e];
            const unsigned urow = ((unsigned)rec.x) >> 16;
            if ((int)(urow >> BIN_SH) == bin && grp == 0) {
                const int lr = (int)(urow & (BIN_ROWS - 1));
                if (lr == lr0 || lr == lr1) {
                    const float v = __int_as_float(rec.y);
                    const f16x8 hv = *(const f16x8*)(h + (size_t)(rec.x & 0xFFFF) * OUT_DIM + (gl << 3));
#pragma unroll
                    for (int j = 0; j < 8; ++j) {
                        if (lr == lr0) a0[j] += v * (float)hv[j];
                        else           a1[j] += v * (float)hv[j];
                    }
                }
            }
        }

#pragma unroll
        for (int j = 0; j < 8; ++j) {
            float x0 = a0[j], x1 = a1[j];
            x0 += __shfl_xor(x0, 16); x0 += __shfl_xor(x0, 32);
            x1 += __shfl_xor(x1, 16); x1 += __shfl_xor(x1, 32);
            a0[j] = x0; a1[j] = x1;
        }

        const int lrow = (grp & 2) ? lr1 : lr0;
        const int grow = (bin << BIN_SH) + lrow;
        float q[4];
#pragma unroll
        for (int k = 0; k < 4; ++k) {
            const float lo = (grp & 2) ? a1[k]     : a0[k];
            const float hi = (grp & 2) ? a1[k + 4] : a0[k + 4];
            q[k] = lrelu((grp & 1) ? hi : lo);
        }
        if (grow < N_NODES) {
            float4 o = make_float4(q[0], q[1], q[2], q[3]);
            *(float4*)(out + (size_t)grow * OUT_DIM + (gl << 3) + ((grp & 1) << 2)) = o;
        }
    }
}

// ---------------------------------------------------------------------------
// Launch: 3 dispatches. prep (coarse || gemm || zero) -> scatter_fine ->
// sort_gather.
// ---------------------------------------------------------------------------
extern "C" void kernel_launch(void* const* d_in, const int* in_sizes, int n_in,
                              void* d_out, int out_size, void* d_ws, size_t ws_size,
                              hipStream_t stream) {
    const float* x    = (const float*)d_in[0];
    const float* w    = (const float*)d_in[1];
    const float* vals = (const float*)d_in[2];
    const int*   rows = (const int*)d_in[3];
    const int*   cols = (const int*)d_in[4];
    float* out = (float*)d_out;

    char* ws = (char*)d_ws;
    size_t off = 0;
    auto alloc = [&](size_t bytes) {
        void* p = ws + off;
        off = (off + bytes + 255) & ~(size_t)255;
        return p;
    };
    int2*   cbuf     = (int2*)  alloc((size_t)N_EDGES * sizeof(int2));               // 12.8 MB
    __half* h        = (__half*)alloc((size_t)N_NODES * OUT_DIM * sizeof(__half));   // 12.8 MB
    int2*   ebuf     = (int2*)  alloc((size_t)NSB * NPART * ECAP * sizeof(int2));    // 16.1 MB
    int2*   ovfbuf   = (int2*)  alloc((size_t)OVF_CAP * sizeof(int2));               // 0.5 MB
    int*    cstartarr= (int*)   alloc((size_t)SCAT_BLOCKS * 50 * sizeof(int));       // 50 KB
    int*    fs       = (int*)   alloc((size_t)NBIN_PAD * NPART * sizeof(int));       // 200 KB
    int*    fc       = (int*)   alloc((size_t)NBIN_PAD * NPART * sizeof(int));       // 200 KB
    int*    ovfcnt   = (int*)   alloc(sizeof(int));

    prep<<<PREP_BLOCKS, 512, 0, stream>>>(rows, cols, vals, x, w,
                                          cstartarr, ovfcnt, cbuf, h);
    scatter_fine<<<NSB * NPART, 512, 0, stream>>>(cstartarr, fs, fc, ovfcnt,
                                                  cbuf, ebuf, ovfbuf);
    sort_gather<<<NBIN_PAD, 256, 0, stream>>>(fs, fc, ovfcnt, ebuf, ovfbuf, h, out);
}